// Round 8
// baseline (1800.266 us; speedup 1.0000x reference)
//
#include <hip/hip_runtime.h>
#include <math.h>

#define TPB 64

// per-block (=per-wave) LDS floats: KV[48][80] + IPT[96] + SZ[48][38]
// KV row layout: K0 [0,18)  K1 [20,38)  V0 [40,58)  V1 [60,78)  (stride 80)
constexpr int LDS_F  = 5760;    // 3840 + 96 + 1824 = 23040 B -> 7 blocks/CU
constexpr int O_IPT  = 3840;
constexpr int O_SZ   = 3936;

// d_ws weight-table offsets (floats)
constexpr int OW_UP  = 0;       // [6][72][18]   up-proj transposed
constexpr int OW_AB  = 7776;    // [6][4][2][36] gate fold (A from xc, B from xm)
constexpr int OW_FUP = 9504;    // [128][18]     FFN up transposed

__device__ __forceinline__ float sigm(float v){ return 1.f/(1.f+__expf(-v)); }
__device__ __forceinline__ float siluf(float v){ return v/(1.f+__expf(-v)); }
__device__ __forceinline__ float logsig(float v){ return fminf(v,0.f) - log1pf(__expf(-fabsf(v))); }

extern "C" __global__ void prep_kernel(
    const float* __restrict__ up,  const float* __restrict__ qw, const float* __restrict__ kw,
    const float* __restrict__ vw,  const float* __restrict__ igw,const float* __restrict__ fgw,
    const float* __restrict__ fup, float* __restrict__ W)
{
  const int tid = threadIdx.x;
  for (int i=tid;i<7776;i+=256){ int mj=i/1296, r=i%1296, o=r/18, d=r%18; W[OW_UP+i]=up[mj*1296+d*72+o]; }
  for (int i=tid;i<1728;i+=256){
    int mj=i/288, r=i%288, gh=r/72, w2=(r%72)/36, c=r%36;
    int g=gh>>1,h=gh&1,n=c>>2,d=c&3;
    const float* gwp=(g? fgw:igw)+mj*216+h*108;
    float val=0.f;
    if(w2==0){ for(int o=0;o<4;++o) val += qw[mj*144+n*16+o*4+d]*gwp[n*4+o] + kw[mj*144+n*16+o*4+d]*gwp[36+n*4+o]; }
    else     { for(int o=0;o<4;++o) val += vw[mj*144+n*16+o*4+d]*gwp[72+n*4+o]; }
    W[OW_AB+i]=val;
  }
  for (int i=tid;i<2304;i+=256){ int f=i/18, d=i%18; W[OW_FUP+i]=fup[d*128+f]; }
}

__device__ __forceinline__ void mlstm(float (&x)[18], const int lane, float* L,
    const float* __restrict__ lnw, const float* __restrict__ wup, const float* __restrict__ wab,
    const float* __restrict__ cw,  const float* __restrict__ cb,
    const float* __restrict__ qw,  const float* __restrict__ kw,  const float* __restrict__ vw,
    const float* __restrict__ igb, const float* __restrict__ fgb, const float* __restrict__ skp,
    const float* __restrict__ onw, const float* __restrict__ dwn /* [36][18] raw */)
{
  float* KV  = L;
  float* IPT = L + O_IPT;
  float* SZ  = L + O_SZ;
  const int sr = (lane<48)? lane : 0;

  // LN
  float mu=0.f;
  #pragma unroll
  for(int d=0;d<18;++d) mu+=x[d];
  mu*=(1.f/18.f);
  float var=0.f;
  #pragma unroll
  for(int d=0;d<18;++d){ float t=x[d]-mu; var+=t*t; }
  var*=(1.f/18.f);
  const float rr=rsqrtf(var+1e-5f);
  float h[18];
  #pragma unroll
  for(int d=0;d<18;++d) h[d]=(x[d]-mu)*rr*lnw[d];

  // group-wise projection: up-proj -> conv -> sz -> k/v -> q -> gates -> skip-fold
  float q[36];
  float gi0=igb[0], gi1=igb[1], gf0=fgb[0], gf1=fgb[1];
  float* kvrow = &KV[lane*80];

  #pragma unroll
  for(int g=0;g<9;++g){
    float xm4[4], xc4[4], sz4[4];
    #pragma unroll
    for(int j=0;j<4;++j){
      const float* w=&wup[(4*g+j)*18];
      float a=0.f;
      #pragma unroll
      for(int d=0;d<18;++d) a+=h[d]*w[d];
      xm4[j]=(lane<48)?a:0.f;            // lanes>=48 feed 0 into conv shuffles
    }
    #pragma unroll
    for(int j=0;j<4;++j){
      const int c=4*g+j;
      const float x1=__shfl(xm4[j],lane-1), x2=__shfl(xm4[j],lane-2), x3=__shfl(xm4[j],lane-3);
      xc4[j]=siluf(cb[c]+x3*cw[c*4]+x2*cw[c*4+1]+x1*cw[c*4+2]+xm4[j]*cw[c*4+3]);
    }
    #pragma unroll
    for(int j=0;j<4;++j){
      const float* w=&wup[(36+4*g+j)*18];
      float a=0.f;
      #pragma unroll
      for(int d=0;d<18;++d) a+=h[d]*w[d];
      sz4[j]=siluf(a);
    }
    if(lane<48){
      float2 s01{sz4[0],sz4[1]}, s23{sz4[2],sz4[3]};
      *reinterpret_cast<float2*>(&SZ[lane*38+4*g])   = s01;
      *reinterpret_cast<float2*>(&SZ[lane*38+4*g+2]) = s23;
    }
    float kt[4], vt[4];
    #pragma unroll
    for(int o=0;o<4;++o){
      const float* wk=&kw[g*16+o*4]; const float* wv=&vw[g*16+o*4];
      kt[o]=xc4[0]*wk[0]+xc4[1]*wk[1]+xc4[2]*wk[2]+xc4[3]*wk[3];
      vt[o]=xm4[0]*wv[0]+xm4[1]*wv[1]+xm4[2]*wv[2]+xm4[3]*wv[3];
    }
    if(lane<48){
      if(g<4){
        float4 kk{kt[0],kt[1],kt[2],kt[3]}, vv{vt[0],vt[1],vt[2],vt[3]};
        *reinterpret_cast<float4*>(&kvrow[4*g])    = kk;
        *reinterpret_cast<float4*>(&kvrow[40+4*g]) = vv;
      } else if(g==4){
        // channels 16,17 -> K0/V0 off 16; channels 18,19 -> K1/V1 off 20
        float2 ka{kt[0],kt[1]}, kb{kt[2],kt[3]}, va{vt[0],vt[1]}, vb{vt[2],vt[3]};
        *reinterpret_cast<float2*>(&kvrow[16]) = ka;
        *reinterpret_cast<float2*>(&kvrow[20]) = kb;
        *reinterpret_cast<float2*>(&kvrow[56]) = va;
        *reinterpret_cast<float2*>(&kvrow[60]) = vb;
      } else {
        const int o=4*g+2;                 // head-1 channels shifted by +2
        float2 ka{kt[0],kt[1]}, kb{kt[2],kt[3]}, va{vt[0],vt[1]}, vb{vt[2],vt[3]};
        *reinterpret_cast<float2*>(&kvrow[o])      = ka;
        *reinterpret_cast<float2*>(&kvrow[o+2])    = kb;
        *reinterpret_cast<float2*>(&kvrow[40+o])   = va;
        *reinterpret_cast<float2*>(&kvrow[40+o+2]) = vb;
      }
    }
    #pragma unroll
    for(int o=0;o<4;++o){
      const float* wq=&qw[g*16+o*4];
      q[4*g+o]=xc4[0]*wq[0]+xc4[1]*wq[1]+xc4[2]*wq[2]+xc4[3]*wq[3];
    }
    #pragma unroll
    for(int j=0;j<4;++j){
      const int c=4*g+j;
      gi0+=xc4[j]*wab[c]     +xm4[j]*wab[36+c];
      gi1+=xc4[j]*wab[72+c]  +xm4[j]*wab[108+c];
      gf0+=xc4[j]*wab[144+c] +xm4[j]*wab[180+c];
      gf1+=xc4[j]*wab[216+c] +xm4[j]*wab[252+c];
    }
    #pragma unroll
    for(int j=0;j<4;++j){
      const int c=4*g+j;
      const float skx=skp[c]*xc4[j]*sz4[j];
      #pragma unroll
      for(int e=0;e<18;++e) x[e]+=skx*dwn[c*18+e];
    }
  }

  // wave prefix scans: lfc (sum of logsig), cummax(ipre-lfc)
  float lf0=logsig(gf0), lf1=logsig(gf1);
  #pragma unroll
  for(int off=1; off<64; off<<=1){
    float t0=__shfl_up(lf0,off), t1=__shfl_up(lf1,off);
    if(lane>=off){ lf0+=t0; lf1+=t1; }
  }
  const float ipt0=gi0-lf0, ipt1=gi1-lf1;
  float u0=ipt0, u1=ipt1;
  #pragma unroll
  for(int off=1; off<64; off<<=1){
    float t0=__shfl_up(u0,off), t1=__shfl_up(u1,off);
    if(lane>=off){ u0=fmaxf(u0,t0); u1=fmaxf(u1,t1); }
  }
  if (lane<48){ float2 w2v{ipt0,ipt1}; *reinterpret_cast<float2*>(&IPT[2*lane])=w2v; }
  asm volatile("s_waitcnt lgkmcnt(0)" ::: "memory");

  // head-split attention; per head: QK+PV pass, normalize, LN, fold through dwn
  const float scl=0.23570226039551584f;
  #pragma unroll
  for(int hh=0;hh<2;++hh){
    const float rb = hh? -u1 : -u0;
    const int kb = hh? 20 : 0;
    const float* qh=&q[hh*18];
    float acc[18];
    #pragma unroll
    for(int d=0;d<18;++d) acc[d]=0.f;
    float rs=0.f;
    for(int t=0;t<48;++t){
      const float ipx = IPT[2*t+hh];
      const float e0=__expf(fminf(rb+ipx,0.f));
      const float* kr=&KV[t*80+kb];
      const float4 k0=*reinterpret_cast<const float4*>(&kr[0]);
      const float4 k1=*reinterpret_cast<const float4*>(&kr[4]);
      const float4 k2=*reinterpret_cast<const float4*>(&kr[8]);
      const float4 k3=*reinterpret_cast<const float4*>(&kr[12]);
      const float2 k4=*reinterpret_cast<const float2*>(&kr[16]);
      float qk = k0.x*qh[0]+k0.y*qh[1]+k0.z*qh[2]+k0.w*qh[3]
               + k1.x*qh[4]+k1.y*qh[5]+k1.z*qh[6]+k1.w*qh[7]
               + k2.x*qh[8]+k2.y*qh[9]+k2.z*qh[10]+k2.w*qh[11]
               + k3.x*qh[12]+k3.y*qh[13]+k3.z*qh[14]+k3.w*qh[15]
               + k4.x*qh[16]+k4.y*qh[17];
      const float c0 = (t<=lane)? qk*scl*e0 : 0.f;
      rs+=c0;
      const float* vr=&KV[t*80+40+kb];
      const float4 v0=*reinterpret_cast<const float4*>(&vr[0]);
      const float4 v1=*reinterpret_cast<const float4*>(&vr[4]);
      const float4 v2=*reinterpret_cast<const float4*>(&vr[8]);
      const float4 v3=*reinterpret_cast<const float4*>(&vr[12]);
      const float2 v4=*reinterpret_cast<const float2*>(&vr[16]);
      acc[0]+=c0*v0.x;  acc[1]+=c0*v0.y;  acc[2]+=c0*v0.z;  acc[3]+=c0*v0.w;
      acc[4]+=c0*v1.x;  acc[5]+=c0*v1.y;  acc[6]+=c0*v1.z;  acc[7]+=c0*v1.w;
      acc[8]+=c0*v2.x;  acc[9]+=c0*v2.y;  acc[10]+=c0*v2.z; acc[11]+=c0*v2.w;
      acc[12]+=c0*v3.x; acc[13]+=c0*v3.y; acc[14]+=c0*v3.z; acc[15]+=c0*v3.w;
      acc[16]+=c0*v4.x; acc[17]+=c0*v4.y;
    }
    const float mr = hh? (lf1+u1) : (lf0+u0);
    const float ninv = 1.f/(fmaxf(fabsf(rs), __expf(-mr))+1e-6f);
    float mu2=0.f;
    #pragma unroll
    for(int d=0;d<18;++d){ acc[d]*=ninv; mu2+=acc[d]; }
    mu2*=(1.f/18.f);
    float vv2=0.f;
    #pragma unroll
    for(int d=0;d<18;++d){ float t=acc[d]-mu2; vv2+=t*t; }
    const float r2=rsqrtf(vv2*(1.f/18.f)+1e-5f);
    #pragma unroll
    for(int cc=0;cc<18;++cc){
      const int c=hh*18+cc;
      const float hn=(acc[cc]-mu2)*r2*onw[c];
      const float hsz=hn*SZ[sr*38+c];
      #pragma unroll
      for(int e=0;e<18;++e) x[e]+=hsz*dwn[c*18+e];
    }
  }
}

__device__ __forceinline__ void slstm(float (&x)[18], const int lane, float* KV,
    const float* __restrict__ lnw, const float* __restrict__ cw, const float* __restrict__ cb,
    const float* __restrict__ gw,  const float* __restrict__ rw, const float* __restrict__ gb,
    const float* __restrict__ gnw, const float* __restrict__ flnw,
    const float* __restrict__ wfup,const float* __restrict__ fdw /* [64][18] raw */)
{
  // LN
  float mu=0.f;
  #pragma unroll
  for(int d=0;d<18;++d) mu+=x[d];
  mu*=(1.f/18.f);
  float var=0.f;
  #pragma unroll
  for(int d=0;d<18;++d){ float t=x[d]-mu; var+=t*t; }
  var*=(1.f/18.f);
  const float rr=rsqrtf(var+1e-5f);
  float h[18];
  #pragma unroll
  for(int d=0;d<18;++d) h[d]=(lane<48)?(x[d]-mu)*rr*lnw[d]:0.f;

  // conv + silu
  float hc[18];
  #pragma unroll
  for(int c=0;c<18;++c){
    float x1=__shfl(h[c], lane-1), x2=__shfl(h[c], lane-2), x3=__shfl(h[c], lane-3);
    float a=cb[c]+x3*cw[c*4]+x2*cw[c*4+1]+x1*cw[c*4+2]+h[c]*cw[c*4+3];
    hc[c]=siluf(a);
  }

  // wx -> KV rows (stride 72): slot (g*2+hh)*9+e
  #pragma unroll
  for(int q4=0;q4<18;++q4){
    float4 t;
    #pragma unroll
    for(int j=0;j<4;++j){
      const int idx=4*q4+j, g=idx/18, hh=(idx%18)/9, e=idx%9;
      const float* inp = (g<2 ? hc : h) + hh*9;
      const float* w=&gw[idx*9];
      float a=gb[idx];
      #pragma unroll
      for(int d=0;d<9;++d) a+=inp[d]*w[d];
      (&t.x)[j]=a;
    }
    if (lane<48) *reinterpret_cast<float4*>(&KV[lane*72+4*q4])=t;
  }
  asm volatile("s_waitcnt lgkmcnt(0)" ::: "memory");

  // scan, one head at a time, wave-synchronous; y written back into consumed slots
  for(int hh=0;hh<2;++hh){
    const int li = (lane<36)? lane : 0;
    const int g=li/9, e=li%9;
    float rwreg[9];
    #pragma unroll
    for(int d=0;d<9;++d) rwreg[d]=rw[((hh*9+d)*4+g)*9+e];
    float yv=0.f,cv=0.f,nv=0.f,mv=0.f;
    for(int st=0;st<48;++st){
      float raw = KV[st*72 + (g*2+hh)*9 + e];
      #pragma unroll
      for(int d=0;d<9;++d) raw += __shfl(yv,d)*rwreg[d];
      const float i_=__shfl(raw,e), f_=__shfl(raw,9+e), z_=__shfl(raw,18+e), o_=__shfl(raw,27+e);
      const float lfm=mv+logsig(f_);
      const float mn=fmaxf(i_,lfm);
      const float ig=__expf(i_-mn), fg=__expf(lfm-mn);
      cv=fg*cv+ig*tanhf(z_);
      nv=fg*nv+ig; mv=mn;
      yv=sigm(o_)*cv/nv;
      if(lane<9) KV[st*72+hh*9+lane]=yv;
    }
  }
  asm volatile("s_waitcnt lgkmcnt(0)" ::: "memory");

  // group norm (per head over 9) + residual
  if (lane<48){
    #pragma unroll
    for(int hh=0;hh<2;++hh){
      float yv_[9]; float m2=0.f;
      #pragma unroll
      for(int e=0;e<9;++e){ yv_[e]=KV[lane*72+hh*9+e]; m2+=yv_[e]; }
      m2*=(1.f/9.f);
      float vv=0.f;
      #pragma unroll
      for(int e=0;e<9;++e){ float t=yv_[e]-m2; vv+=t*t; }
      const float r2=rsqrtf(vv*(1.f/9.f)+1e-5f);
      #pragma unroll
      for(int e=0;e<9;++e) x[hh*9+e]+=(yv_[e]-m2)*r2*gnw[hh*9+e];
    }
  }

  // FFN: LN -> h2; per-f activation accumulated straight into x
  float mu2=0.f;
  #pragma unroll
  for(int d=0;d<18;++d) mu2+=x[d];
  mu2*=(1.f/18.f);
  float var2=0.f;
  #pragma unroll
  for(int d=0;d<18;++d){ float t=x[d]-mu2; var2+=t*t; }
  var2*=(1.f/18.f);
  const float rr2=rsqrtf(var2+1e-5f);
  float h2[18];
  #pragma unroll
  for(int d=0;d<18;++d) h2[d]=(x[d]-mu2)*rr2*flnw[d];

  #pragma unroll
  for(int f=0;f<64;++f){
    const float* wg=&wfup[f*18]; const float* wu=&wfup[(64+f)*18];
    float ug=0.f, uu=0.f;
    #pragma unroll
    for(int d=0;d<18;++d){ ug+=h2[d]*wg[d]; uu+=h2[d]*wu[d]; }
    const float ge=0.5f*ug*(1.f+erff(ug*0.70710678118654752f));
    const float actf=ge*uu;
    #pragma unroll
    for(int e=0;e<18;++e) x[e]+=actf*fdw[f*18+e];
  }
}

extern "C" __global__ void __launch_bounds__(TPB, 2)
xlstm_kernel(const float* __restrict__ gx,
             const float* __restrict__ m_ln_w,  const float* __restrict__ m_conv_w,
             const float* __restrict__ m_conv_b,const float* __restrict__ m_q_w,
             const float* __restrict__ m_k_w,   const float* __restrict__ m_v_w,
             const float* __restrict__ m_ig_b,  const float* __restrict__ m_fg_b,
             const float* __restrict__ m_skip,  const float* __restrict__ m_on_w,
             const float* __restrict__ m_down_w,
             const float* __restrict__ s_ln_w,  const float* __restrict__ s_conv_w,
             const float* __restrict__ s_conv_b,const float* __restrict__ s_gate_w,
             const float* __restrict__ s_rec_w, const float* __restrict__ s_bias,
             const float* __restrict__ s_gn_w,  const float* __restrict__ f_ln_w,
             const float* __restrict__ f_down_w,
             const float* __restrict__ post_ln_w, const float* __restrict__ dense_w,
             const float* __restrict__ dense_b, const float* __restrict__ W,
             float* __restrict__ gout)
{
  __shared__ float L[LDS_F];
  const int lane = threadIdx.x;
  const int b = blockIdx.x;

  float x[18];
  #pragma unroll
  for(int d=0;d<18;++d) x[d] = (lane<48) ? gx[b*864 + lane*18 + d] : 0.f;

  int mj=0;
  #pragma unroll 1
  for(int blk=0; blk<7; ++blk){
    if (blk==1){
      slstm(x, lane, L, s_ln_w, s_conv_w, s_conv_b, s_gate_w, s_rec_w, s_bias,
            s_gn_w, f_ln_w, W+OW_FUP, f_down_w);
    } else {
      mlstm(x, lane, L,
            m_ln_w+mj*18, W+OW_UP+mj*1296, W+OW_AB+mj*288,
            m_conv_w+mj*144, m_conv_b+mj*36,
            m_q_w+mj*144, m_k_w+mj*144, m_v_w+mj*144,
            m_ig_b+mj*2, m_fg_b+mj*2, m_skip+mj*36, m_on_w+mj*36,
            m_down_w+mj*648);
      ++mj;
    }
  }

  // post-LN + dense(18->1), zero s<24
  if (lane<48){
    float mu=0.f;
    #pragma unroll
    for(int d=0;d<18;++d) mu+=x[d];
    mu*=(1.f/18.f);
    float var=0.f;
    #pragma unroll
    for(int d=0;d<18;++d){ float t=x[d]-mu; var+=t*t; }
    var*=(1.f/18.f);
    const float rr=rsqrtf(var+1e-5f);
    float acc=dense_b[0];
    #pragma unroll
    for(int d=0;d<18;++d) acc += (x[d]-mu)*rr*post_ln_w[d]*dense_w[d];
    gout[b*48+lane] = (lane<24) ? 0.f : acc;
  }
}

extern "C" void kernel_launch(void* const* d_in, const int* in_sizes, int n_in,
                              void* d_out, int out_size, void* d_ws, size_t ws_size,
                              hipStream_t stream)
{
  const float* gx        = (const float*)d_in[0];
  const float* m_ln_w    = (const float*)d_in[1];
  const float* m_up_w    = (const float*)d_in[2];
  const float* m_conv_w  = (const float*)d_in[3];
  const float* m_conv_b  = (const float*)d_in[4];
  const float* m_q_w     = (const float*)d_in[5];
  const float* m_k_w     = (const float*)d_in[6];
  const float* m_v_w     = (const float*)d_in[7];
  const float* m_ig_w    = (const float*)d_in[8];
  const float* m_ig_b    = (const float*)d_in[9];
  const float* m_fg_w    = (const float*)d_in[10];
  const float* m_fg_b    = (const float*)d_in[11];
  const float* m_skip    = (const float*)d_in[12];
  const float* m_on_w    = (const float*)d_in[13];
  const float* m_down_w  = (const float*)d_in[14];
  const float* s_ln_w    = (const float*)d_in[15];
  const float* s_conv_w  = (const float*)d_in[16];
  const float* s_conv_b  = (const float*)d_in[17];
  const float* s_gate_w  = (const float*)d_in[18];
  const float* s_rec_w   = (const float*)d_in[19];
  const float* s_bias    = (const float*)d_in[20];
  const float* s_gn_w    = (const float*)d_in[21];
  const float* f_ln_w    = (const float*)d_in[22];
  const float* f_up_w    = (const float*)d_in[23];
  const float* f_down_w  = (const float*)d_in[24];
  const float* post_ln_w = (const float*)d_in[25];
  const float* dense_w   = (const float*)d_in[26];
  const float* dense_b   = (const float*)d_in[27];

  float* W = (float*)d_ws;
  const int B = in_sizes[0] / (48*18);

  prep_kernel<<<1, 256, 0, stream>>>(m_up_w, m_q_w, m_k_w, m_v_w, m_ig_w, m_fg_w,
                                     f_up_w, W);
  xlstm_kernel<<<B, TPB, 0, stream>>>(gx,
    m_ln_w, m_conv_w, m_conv_b, m_q_w, m_k_w, m_v_w,
    m_ig_b, m_fg_b, m_skip, m_on_w, m_down_w,
    s_ln_w, s_conv_w, s_conv_b, s_gate_w, s_rec_w, s_bias, s_gn_w,
    f_ln_w, f_down_w, post_ln_w, dense_w, dense_b, W, (float*)d_out);
}